// Round 10
// baseline (256.660 us; speedup 1.0000x reference)
//
#include <hip/hip_runtime.h>
#include <hip/hip_cooperative_groups.h>

namespace cg = cooperative_groups;

#define DIM_HID 65536
#define NKERS   500
#define ROWS_PB 4                     // rows per gemv block
#define NCHUNK  16                    // chunks per row
#define CHUNK   (DIM_HID / NCHUNK)    // 4096 floats = 1024 float4 per chunk
#define NBLK    ((NKERS / ROWS_PB) * NCHUNK)   // 2000

typedef float f4 __attribute__((ext_vector_type(4)));

// ---------- proven R8 pieces (no nt: R6/R7 isolated nt at -0.8us) ----------

__device__ __forceinline__ void gemv_phase(
    const float* __restrict__ W, const float* __restrict__ x,
    float* __restrict__ ws, int bid, int t, float (*wsum)[4])
{
    const int rg  = bid >> 4;         // rowgroup 0..124
    const int q   = bid & 15;         // chunk 0..15
    const int r0  = rg * ROWS_PB;
    const int wave = t >> 6;
    const int lane = t & 63;

    const size_t base = (size_t)r0 * DIM_HID + (size_t)q * CHUNK;
    const f4* __restrict__ W0 = reinterpret_cast<const f4*>(W + base);
    const f4* __restrict__ W1 = reinterpret_cast<const f4*>(W + base + DIM_HID);
    const f4* __restrict__ W2 = reinterpret_cast<const f4*>(W + base + 2 * DIM_HID);
    const f4* __restrict__ W3 = reinterpret_cast<const f4*>(W + base + 3 * DIM_HID);
    const f4* __restrict__ xq = reinterpret_cast<const f4*>(x + q * CHUNK);

    float s0 = 0.0f, s1 = 0.0f, s2 = 0.0f, s3 = 0.0f;
#pragma unroll 2
    for (int k = 0; k < 4; ++k) {
        const int idx = t + k * 256;                // coalesced
        const f4 v  = xq[idx];
        const f4 w0 = W0[idx];
        const f4 w1 = W1[idx];
        const f4 w2 = W2[idx];
        const f4 w3 = W3[idx];
        s0 = fmaf(w0.x, v.x, s0); s0 = fmaf(w0.y, v.y, s0);
        s0 = fmaf(w0.z, v.z, s0); s0 = fmaf(w0.w, v.w, s0);
        s1 = fmaf(w1.x, v.x, s1); s1 = fmaf(w1.y, v.y, s1);
        s1 = fmaf(w1.z, v.z, s1); s1 = fmaf(w1.w, v.w, s1);
        s2 = fmaf(w2.x, v.x, s2); s2 = fmaf(w2.y, v.y, s2);
        s2 = fmaf(w2.z, v.z, s2); s2 = fmaf(w2.w, v.w, s2);
        s3 = fmaf(w3.x, v.x, s3); s3 = fmaf(w3.y, v.y, s3);
        s3 = fmaf(w3.z, v.z, s3); s3 = fmaf(w3.w, v.w, s3);
    }

#pragma unroll
    for (int off = 32; off > 0; off >>= 1) {
        s0 += __shfl_down(s0, off, 64);
        s1 += __shfl_down(s1, off, 64);
        s2 += __shfl_down(s2, off, 64);
        s3 += __shfl_down(s3, off, 64);
    }

    if (lane == 0) {
        wsum[wave][0] = s0; wsum[wave][1] = s1;
        wsum[wave][2] = s2; wsum[wave][3] = s3;
    }
    __syncthreads();

    if (t < 4) {
        float a = wsum[0][t] + wsum[1][t] + wsum[2][t] + wsum[3][t];
        ws[(size_t)(r0 + t) * NCHUNK + q] = a;
    }
}

__device__ __forceinline__ void expand_phase(
    const float* __restrict__ ws, const float* __restrict__ bias,
    const float* __restrict__ kernels, const int* __restrict__ kw,
    float* __restrict__ z, int j, int t, float (*wsum)[4])
{
    const int wave = t >> 6;
    const int lane = t & 63;
    const f4* __restrict__ wsv = reinterpret_cast<const f4*>(ws);

    float acc = 0.0f;
#pragma unroll
    for (int k = 0; k < 2; ++k) {
        const int i = t + k * 256;
        if (i < NKERS) {
            const f4 p0 = wsv[i * 4 + 0];
            const f4 p1 = wsv[i * 4 + 1];
            const f4 p2 = wsv[i * 4 + 2];
            const f4 p3 = wsv[i * 4 + 3];
            const float yi = (((p0.x + p0.y) + (p0.z + p0.w)) +
                              ((p1.x + p1.y) + (p1.z + p1.w))) +
                             (((p2.x + p2.y) + (p2.z + p2.w)) +
                              ((p3.x + p3.y) + (p3.z + p3.w))) + bias[i];
            const int   w  = kw[i];
            const float kv = kernels[i * NKERS + j];
            if (j < w) acc = fmaf(yi, kv, acc);
        }
    }

#pragma unroll
    for (int off = 32; off > 0; off >>= 1)
        acc += __shfl_down(acc, off, 64);

    __syncthreads();
    if (lane == 0) wsum[0][wave] = acc;
    __syncthreads();

    if (t == 0)
        z[j] = (wsum[0][0] + wsum[0][1]) + (wsum[0][2] + wsum[0][3]);
}

// ---------- path A: fused cooperative kernel ----------
__global__ __launch_bounds__(256, 8) void fused_kernel(
    const float* __restrict__ W, const float* __restrict__ x,
    const float* __restrict__ bias, const float* __restrict__ kernels,
    const int* __restrict__ kw, float* __restrict__ ws, float* __restrict__ z)
{
    __shared__ float wsum[4][4];
    const int bid = blockIdx.x;
    const int t   = threadIdx.x;

    gemv_phase(W, x, ws, bid, t, wsum);
    cg::this_grid().sync();
    if (bid < NKERS)
        expand_phase(ws, bias, kernels, kw, z, bid, t, wsum);
}

// ---------- path B: proven R8 two-kernel fallback ----------
__global__ __launch_bounds__(256, 8) void gemv_part_kernel(
    const float* __restrict__ W, const float* __restrict__ x,
    float* __restrict__ ws)
{
    __shared__ float wsum[4][4];
    gemv_phase(W, x, ws, blockIdx.x, threadIdx.x, wsum);
}

__global__ __launch_bounds__(256) void expand_kernel(
    const float* __restrict__ ws, const float* __restrict__ bias,
    const float* __restrict__ kernels, const int* __restrict__ kw,
    float* __restrict__ z)
{
    __shared__ float wsum[4][4];
    expand_phase(ws, bias, kernels, kw, z, blockIdx.x, threadIdx.x, wsum);
}

extern "C" void kernel_launch(void* const* d_in, const int* in_sizes, int n_in,
                              void* d_out, int out_size, void* d_ws, size_t ws_size,
                              hipStream_t stream)
{
    const float* input   = (const float*)d_in[0];  // [65536]
    const float* weight  = (const float*)d_in[1];  // [500, 65536]
    const float* bias    = (const float*)d_in[2];  // [500]
    const float* kernels = (const float*)d_in[3];  // [500, 500]
    const int*   kwidths = (const int*)d_in[4];    // [500]
    float* z  = (float*)d_out;                     // [500]
    float* ws = (float*)d_ws;                      // [500*16] gemv partials

    void* args[] = {(void*)&weight, (void*)&input, (void*)&bias,
                    (void*)&kernels, (void*)&kwidths, (void*)&ws, (void*)&z};
    hipError_t rc = hipLaunchCooperativeKernel((const void*)fused_kernel,
                                               dim3(NBLK), dim3(256),
                                               args, 0, stream);
    if (rc != hipSuccess) {
        // deterministic fallback: identical math, two launches
        gemv_part_kernel<<<NBLK, 256, 0, stream>>>(weight, input, ws);
        expand_kernel<<<NKERS, 256, 0, stream>>>(ws, bias, kernels, kwidths, z);
    }
}

// Round 11
// 28.601 us; speedup vs baseline: 8.9737x; 8.9737x over previous
//
#include <hip/hip_runtime.h>

#define DIM_HID 65536
#define NKERS   500
#define ROWS_PB 4                     // rows per gemv block
#define NCHUNK  16                    // chunks per row
#define CHUNK   (DIM_HID / NCHUNK)    // 4096 floats = 1024 float4 per chunk
#define NBLK    ((NKERS / ROWS_PB) * NCHUNK)   // 2000

typedef float f4 __attribute__((ext_vector_type(4)));

// Kernel 1: partial GEMV, 4 rows x 1/16 row per block (R8 structure, proven
// 5.95 TB/s). Plain cacheable W loads: R6-vs-R7 isolated nt at -0.8us.
// 2000 blocks x 256 threads; launch_bounds(256,8) -> <=64 VGPR, 32 waves/CU.
// Each x-load feeds 4 rows' fmas (x-load share 20% of vm instructions).
__global__ __launch_bounds__(256, 8) void gemv_part_kernel(
    const float* __restrict__ W,
    const float* __restrict__ x,
    float* __restrict__ ws)
{
    const int bid = blockIdx.x;           // 0..1999
    const int rg  = bid >> 4;             // rowgroup 0..124
    const int q   = bid & 15;             // chunk 0..15
    const int r0  = rg * ROWS_PB;
    const int t   = threadIdx.x;

    const size_t base = (size_t)r0 * DIM_HID + (size_t)q * CHUNK;
    const f4* __restrict__ W0 = reinterpret_cast<const f4*>(W + base);
    const f4* __restrict__ W1 = reinterpret_cast<const f4*>(W + base + DIM_HID);
    const f4* __restrict__ W2 = reinterpret_cast<const f4*>(W + base + 2 * DIM_HID);
    const f4* __restrict__ W3 = reinterpret_cast<const f4*>(W + base + 3 * DIM_HID);
    const f4* __restrict__ xq = reinterpret_cast<const f4*>(x + q * CHUNK);

    float s0 = 0.0f, s1 = 0.0f, s2 = 0.0f, s3 = 0.0f;
#pragma unroll 2
    for (int k = 0; k < 4; ++k) {
        const int idx = t + k * 256;                    // coalesced
        const f4 v  = xq[idx];
        const f4 w0 = W0[idx];
        const f4 w1 = W1[idx];
        const f4 w2 = W2[idx];
        const f4 w3 = W3[idx];
        s0 = fmaf(w0.x, v.x, s0); s0 = fmaf(w0.y, v.y, s0);
        s0 = fmaf(w0.z, v.z, s0); s0 = fmaf(w0.w, v.w, s0);
        s1 = fmaf(w1.x, v.x, s1); s1 = fmaf(w1.y, v.y, s1);
        s1 = fmaf(w1.z, v.z, s1); s1 = fmaf(w1.w, v.w, s1);
        s2 = fmaf(w2.x, v.x, s2); s2 = fmaf(w2.y, v.y, s2);
        s2 = fmaf(w2.z, v.z, s2); s2 = fmaf(w2.w, v.w, s2);
        s3 = fmaf(w3.x, v.x, s3); s3 = fmaf(w3.y, v.y, s3);
        s3 = fmaf(w3.z, v.z, s3); s3 = fmaf(w3.w, v.w, s3);
    }

    // wave reduce all four accumulators
#pragma unroll
    for (int off = 32; off > 0; off >>= 1) {
        s0 += __shfl_down(s0, off, 64);
        s1 += __shfl_down(s1, off, 64);
        s2 += __shfl_down(s2, off, 64);
        s3 += __shfl_down(s3, off, 64);
    }

    __shared__ float wsum[4][4];   // [wave][row]
    const int wave = t >> 6;
    const int lane = t & 63;
    if (lane == 0) {
        wsum[wave][0] = s0; wsum[wave][1] = s1;
        wsum[wave][2] = s2; wsum[wave][3] = s3;
    }
    __syncthreads();

    if (t < 4) {   // thread rr writes row r0+rr
        float a = wsum[0][t] + wsum[1][t] + wsum[2][t] + wsum[3][t];
        ws[(size_t)(r0 + t) * NCHUNK + q] = a;
    }
}

// Kernel 2: z[j] = sum_i y_i * kernels[i][j] * (j < kw[i]),
// y_i = sum of 16 gemv partials + bias[i]. One block per j, 500x256.
__global__ __launch_bounds__(256) void expand_kernel(
    const float* __restrict__ ws,
    const float* __restrict__ bias,
    const float* __restrict__ kernels,
    const int* __restrict__ kw,
    float* __restrict__ z)
{
    const int j = blockIdx.x;
    const int t = threadIdx.x;
    const f4* __restrict__ wsv = reinterpret_cast<const f4*>(ws);

    float acc = 0.0f;
#pragma unroll
    for (int k = 0; k < 2; ++k) {
        const int i = t + k * 256;
        if (i < NKERS) {
            const f4 p0 = wsv[i * 4 + 0];
            const f4 p1 = wsv[i * 4 + 1];
            const f4 p2 = wsv[i * 4 + 2];
            const f4 p3 = wsv[i * 4 + 3];
            const float yi = (((p0.x + p0.y) + (p0.z + p0.w)) +
                              ((p1.x + p1.y) + (p1.z + p1.w))) +
                             (((p2.x + p2.y) + (p2.z + p2.w)) +
                              ((p3.x + p3.y) + (p3.z + p3.w))) + bias[i];
            const int   w  = kw[i];
            const float kv = kernels[i * NKERS + j];
            if (j < w) acc = fmaf(yi, kv, acc);
        }
    }

#pragma unroll
    for (int off = 32; off > 0; off >>= 1)
        acc += __shfl_down(acc, off, 64);

    __shared__ float wsum[4];
    const int wave = t >> 6;
    const int lane = t & 63;
    if (lane == 0) wsum[wave] = acc;
    __syncthreads();

    if (t == 0)
        z[j] = (wsum[0] + wsum[1]) + (wsum[2] + wsum[3]);
}

extern "C" void kernel_launch(void* const* d_in, const int* in_sizes, int n_in,
                              void* d_out, int out_size, void* d_ws, size_t ws_size,
                              hipStream_t stream)
{
    const float* input   = (const float*)d_in[0];  // [65536]
    const float* weight  = (const float*)d_in[1];  // [500, 65536]
    const float* bias    = (const float*)d_in[2];  // [500]
    const float* kernels = (const float*)d_in[3];  // [500, 500]
    const int*   kwidths = (const int*)d_in[4];    // [500]
    float* z  = (float*)d_out;                     // [500]
    float* ws = (float*)d_ws;                      // [500*16] gemv partials

    gemv_part_kernel<<<NBLK, 256, 0, stream>>>(weight, input, ws);
    expand_kernel<<<NKERS, 256, 0, stream>>>(ws, bias, kernels, kwidths, z);
}

// Round 12
// 27.123 us; speedup vs baseline: 9.4630x; 1.0545x over previous
//
#include <hip/hip_runtime.h>

#define DIM_HID 65536
#define NKERS   500
#define ROWS_PB 4                     // rows per gemv block
#define NCHUNK  16                    // chunks per row
#define CHUNK   (DIM_HID / NCHUNK)    // 4096 floats = 1024 float4 per chunk
#define NBLK    ((NKERS / ROWS_PB) * NCHUNK)   // 2000

typedef float f4 __attribute__((ext_vector_type(4)));

// Kernel 1: partial GEMV, 4 rows x 1/16 row per block. R8 config exactly:
// nt on W loads (R8 27.27 vs R11-no-nt 28.60: nt = -1.3us in THIS structure —
// 4 streamed W rows/block would thrash L1/L2 and evict the reused x chunk).
// 2000 blocks x 256 threads; launch_bounds(256,8) -> <=64 VGPR, 32 waves/CU.
__global__ __launch_bounds__(256, 8) void gemv_part_kernel(
    const float* __restrict__ W,
    const float* __restrict__ x,
    float* __restrict__ ws)
{
    const int bid = blockIdx.x;           // 0..1999
    const int rg  = bid >> 4;             // rowgroup 0..124
    const int q   = bid & 15;             // chunk 0..15
    const int r0  = rg * ROWS_PB;
    const int t   = threadIdx.x;

    const size_t base = (size_t)r0 * DIM_HID + (size_t)q * CHUNK;
    const f4* __restrict__ W0 = reinterpret_cast<const f4*>(W + base);
    const f4* __restrict__ W1 = reinterpret_cast<const f4*>(W + base + DIM_HID);
    const f4* __restrict__ W2 = reinterpret_cast<const f4*>(W + base + 2 * DIM_HID);
    const f4* __restrict__ W3 = reinterpret_cast<const f4*>(W + base + 3 * DIM_HID);
    const f4* __restrict__ xq = reinterpret_cast<const f4*>(x + q * CHUNK);

    float s0 = 0.0f, s1 = 0.0f, s2 = 0.0f, s3 = 0.0f;
#pragma unroll 2
    for (int k = 0; k < 4; ++k) {
        const int idx = t + k * 256;                    // coalesced
        const f4 v  = xq[idx];
        const f4 w0 = __builtin_nontemporal_load(&W0[idx]);
        const f4 w1 = __builtin_nontemporal_load(&W1[idx]);
        const f4 w2 = __builtin_nontemporal_load(&W2[idx]);
        const f4 w3 = __builtin_nontemporal_load(&W3[idx]);
        s0 = fmaf(w0.x, v.x, s0); s0 = fmaf(w0.y, v.y, s0);
        s0 = fmaf(w0.z, v.z, s0); s0 = fmaf(w0.w, v.w, s0);
        s1 = fmaf(w1.x, v.x, s1); s1 = fmaf(w1.y, v.y, s1);
        s1 = fmaf(w1.z, v.z, s1); s1 = fmaf(w1.w, v.w, s1);
        s2 = fmaf(w2.x, v.x, s2); s2 = fmaf(w2.y, v.y, s2);
        s2 = fmaf(w2.z, v.z, s2); s2 = fmaf(w2.w, v.w, s2);
        s3 = fmaf(w3.x, v.x, s3); s3 = fmaf(w3.y, v.y, s3);
        s3 = fmaf(w3.z, v.z, s3); s3 = fmaf(w3.w, v.w, s3);
    }

    // wave reduce all four accumulators
#pragma unroll
    for (int off = 32; off > 0; off >>= 1) {
        s0 += __shfl_down(s0, off, 64);
        s1 += __shfl_down(s1, off, 64);
        s2 += __shfl_down(s2, off, 64);
        s3 += __shfl_down(s3, off, 64);
    }

    __shared__ float wsum[4][4];   // [wave][row]
    const int wave = t >> 6;
    const int lane = t & 63;
    if (lane == 0) {
        wsum[wave][0] = s0; wsum[wave][1] = s1;
        wsum[wave][2] = s2; wsum[wave][3] = s3;
    }
    __syncthreads();

    if (t < 4) {   // thread rr writes row r0+rr
        float a = wsum[0][t] + wsum[1][t] + wsum[2][t] + wsum[3][t];
        ws[(size_t)(r0 + t) * NCHUNK + q] = a;
    }
}

// Kernel 2: z[j] = sum_i y_i * kernels[i][j] * (j < kw[i]),
// y_i = sum of 16 gemv partials + bias[i]. One block per j, 500x256.
__global__ __launch_bounds__(256) void expand_kernel(
    const float* __restrict__ ws,
    const float* __restrict__ bias,
    const float* __restrict__ kernels,
    const int* __restrict__ kw,
    float* __restrict__ z)
{
    const int j = blockIdx.x;
    const int t = threadIdx.x;
    const f4* __restrict__ wsv = reinterpret_cast<const f4*>(ws);

    float acc = 0.0f;
#pragma unroll
    for (int k = 0; k < 2; ++k) {
        const int i = t + k * 256;
        if (i < NKERS) {
            const f4 p0 = wsv[i * 4 + 0];
            const f4 p1 = wsv[i * 4 + 1];
            const f4 p2 = wsv[i * 4 + 2];
            const f4 p3 = wsv[i * 4 + 3];
            const float yi = (((p0.x + p0.y) + (p0.z + p0.w)) +
                              ((p1.x + p1.y) + (p1.z + p1.w))) +
                             (((p2.x + p2.y) + (p2.z + p2.w)) +
                              ((p3.x + p3.y) + (p3.z + p3.w))) + bias[i];
            const int   w  = kw[i];
            const float kv = kernels[i * NKERS + j];
            if (j < w) acc = fmaf(yi, kv, acc);
        }
    }

#pragma unroll
    for (int off = 32; off > 0; off >>= 1)
        acc += __shfl_down(acc, off, 64);

    __shared__ float wsum[4];
    const int wave = t >> 6;
    const int lane = t & 63;
    if (lane == 0) wsum[wave] = acc;
    __syncthreads();

    if (t == 0)
        z[j] = (wsum[0] + wsum[1]) + (wsum[2] + wsum[3]);
}

extern "C" void kernel_launch(void* const* d_in, const int* in_sizes, int n_in,
                              void* d_out, int out_size, void* d_ws, size_t ws_size,
                              hipStream_t stream)
{
    const float* input   = (const float*)d_in[0];  // [65536]
    const float* weight  = (const float*)d_in[1];  // [500, 65536]
    const float* bias    = (const float*)d_in[2];  // [500]
    const float* kernels = (const float*)d_in[3];  // [500, 500]
    const int*   kwidths = (const int*)d_in[4];    // [500]
    float* z  = (float*)d_out;                     // [500]
    float* ws = (float*)d_ws;                      // [500*16] gemv partials

    gemv_part_kernel<<<NBLK, 256, 0, stream>>>(weight, input, ws);
    expand_kernel<<<NKERS, 256, 0, stream>>>(ws, bias, kernels, kwidths, z);
}